// Round 4
// baseline (84.212 us; speedup 1.0000x reference)
//
#include <hip/hip_runtime.h>
#include <math.h>

#define POOL 7
#define NUM_ROIS 300
#define FH 50
#define FW 50
#define FC 512
#define NBINS (POOL * POOL)                    // 49 bins per ROI
#define OUT_F4 (NBINS * FC / 4)                // 6272 float4 per ROI

typedef float floatx4 __attribute__((ext_vector_type(4)));  // native vec for nontemporal

// Fully fused: one block per ROI, 1024 threads, ZERO workspace use.
// Phase 1: per-pixel channel-max of the ROI's rect only, straight from the
//          feature map (L2/L3-resident, 5.12 MB total). 64 groups of 16
//          lanes; each group reduces one pixel's 512 channels (8 independent
//          float4 loads/lane -> good MLP, 4-step shfl_xor reduce).
// Phase 2: lanes 0..48 compute the 49 bin maxima from the LDS rect.
// Phase 3: all 16 waves stream the 49x512 broadcast slice (100 KB/block,
//          30 MB total = output floor) with nontemporal float4 stores.
__global__ __launch_bounds__(1024) void roi_pool_fused(
    const float* __restrict__ rois, const float* __restrict__ fm,
    float* __restrict__ out) {
    __shared__ float sf[FH * FW];               // ROI-relative pixel maxima (<=10 KB)
    __shared__ float pooled[NBINS];
    int n = blockIdx.x;                         // roi
    int t = threadIdx.x;

    // Replicate: r = int32(roi * (1/16)) (truncation; values non-negative).
    int x1 = (int)(rois[n * 5 + 1] * 0.0625f);
    int y1 = (int)(rois[n * 5 + 2] * 0.0625f);
    int x2 = (int)(rois[n * 5 + 3] * 0.0625f);
    int y2 = (int)(rois[n * 5 + 4] * 0.0625f);
    int rh = y2 - y1 + 1;
    int rw = x2 - x1 + 1;
    // Clipped rect actually touched by bins (bins clip to [0,FH)/[0,FW)).
    int y2c = min(y2, FH - 1), x2c = min(x2, FW - 1);
    int rhc = y2c - y1 + 1, rwc = x2c - x1 + 1; // rect dims; rhc*rwc <= 2500
    int npix = rhc * rwc;

    // Phase 1: group g handles pixels g, g+64, ... of the rect.
    int grp = t >> 4, gl = t & 15;
    for (int p = grp; p < npix; p += 64) {
        int ph = p / rwc;                       // group-uniform int div
        int hh = y1 + ph;
        int ww = x1 + (p - ph * rwc);
        const float4* q = (const float4*)(fm + (size_t)(hh * FW + ww) * FC);
        float m = -INFINITY;
        #pragma unroll
        for (int r = 0; r < 8; ++r) {           // 8 independent 16B loads
            float4 v = q[gl + 16 * r];
            m = fmaxf(m, fmaxf(fmaxf(v.x, v.y), fmaxf(v.z, v.w)));
        }
        #pragma unroll
        for (int off = 8; off > 0; off >>= 1)   // reduce across the 16 lanes
            m = fmaxf(m, __shfl_xor(m, off, 64));
        if (gl == 0) sf[p] = m;
    }
    __syncthreads();

    // Phase 2: bin maxima. Python floor-div on non-negative ints == C division.
    if (t < NBINS) {
        int i = t / POOL;                       // row bin
        int j = t - i * POOL;                   // col bin
        int hs = min(max(y1 + (i * rh) / POOL, 0), FH);
        int he = min(max(y1 + ((i + 1) * rh + POOL - 1) / POOL, 0), FH);
        int ws = min(max(x1 + (j * rw) / POOL, 0), FW);
        int we = min(max(x1 + ((j + 1) * rw + POOL - 1) / POOL, 0), FW);
        float m = -INFINITY;                    // empty bin -> -inf (matches ref)
        for (int h = hs; h < he; ++h)           // hs >= y1, he <= y2c+1 (proven)
            for (int w = ws; w < we; ++w)
                m = fmaxf(m, sf[(h - y1) * rwc + (w - x1)]);
        pooled[t] = m;
    }
    __syncthreads();

    // Phase 3: stream out 49*512 floats = 6272 float4; bin index = f4 >> 7.
    floatx4* o4 = (floatx4*)(out + (size_t)n * NBINS * FC);
    for (int f = t; f < OUT_F4; f += 1024) {
        float m = pooled[f >> 7];
        floatx4 v = {m, m, m, m};
        __builtin_nontemporal_store(v, &o4[f]);
    }
}

extern "C" void kernel_launch(void* const* d_in, const int* in_sizes, int n_in,
                              void* d_out, int out_size, void* d_ws, size_t ws_size,
                              hipStream_t stream) {
    const float* rois = (const float*)d_in[0];          // (300, 5) f32
    const float* feature_maps = (const float*)d_in[1];  // (50, 50, 512) f32
    float* out = (float*)d_out;                         // (300, 7, 7, 512) f32
    (void)d_ws; (void)ws_size;                          // workspace unused

    roi_pool_fused<<<NUM_ROIS, 1024, 0, stream>>>(rois, feature_maps, out);
}

// Round 5
// 75.663 us; speedup vs baseline: 1.1130x; 1.1130x over previous
//
#include <hip/hip_runtime.h>
#include <math.h>

#define POOL 7
#define NUM_ROIS 300
#define FH 50
#define FW 50
#define FC 512
#define NBINS (POOL * POOL)                    // 49 bins per ROI
#define FMAX_N (FH * FW)                       // 2500 pixels
#define OUT_F4 (NBINS * FC / 4)                // 6272 float4 per ROI
#define TOTAL_F4 (NUM_ROIS * OUT_F4)           // 1,881,600 float4 = 30.1 MB

typedef float floatx4 __attribute__((ext_vector_type(4)));  // native vec for nontemporal

// K1: fmax[h][w] = max over C of feature_maps[h][w][c]
// 256-thread blocks, one wave per pixel (4 pixels/block) -> 625 workgroups, ~2 us.
__global__ __launch_bounds__(256) void channel_max_kernel(
    const float* __restrict__ fm, float* __restrict__ fmax_g) {
    int wave = threadIdx.x >> 6;
    int lane = threadIdx.x & 63;
    int pix = blockIdx.x * 4 + wave;            // 0..2499
    const float4* p = (const float4*)(fm + (size_t)pix * FC);
    float4 a = p[lane];
    float4 b = p[lane + 64];
    float m = fmaxf(fmaxf(fmaxf(a.x, a.y), fmaxf(a.z, a.w)),
                    fmaxf(fmaxf(b.x, b.y), fmaxf(b.z, b.w)));
    #pragma unroll
    for (int off = 32; off > 0; off >>= 1)
        m = fmaxf(m, __shfl_down(m, off, 64));
    if (lane == 0) fmax_g[pix] = m;
}

// K2: pooled_g[n][bin] for all 300 ROIs. One 256-thread block per ROI:
// stage 10 KB fmax into LDS (coalesced), then lanes 0..48 compute bin maxima.
__global__ __launch_bounds__(256) void pool_kernel(
    const float* __restrict__ rois, const float* __restrict__ fmax_g,
    float* __restrict__ pooled_g) {
    __shared__ float sf[FMAX_N];
    int n = blockIdx.x;                         // roi
    int t = threadIdx.x;

    for (int idx = t; idx < FMAX_N; idx += 256)
        sf[idx] = fmax_g[idx];
    __syncthreads();

    if (t < NBINS) {
        int i = t / POOL;                       // row bin
        int j = t - i * POOL;                   // col bin

        // Replicate: r = int32(roi * (1/16)) (truncation; values non-negative).
        int x1 = (int)(rois[n * 5 + 1] * 0.0625f);
        int y1 = (int)(rois[n * 5 + 2] * 0.0625f);
        int x2 = (int)(rois[n * 5 + 3] * 0.0625f);
        int y2 = (int)(rois[n * 5 + 4] * 0.0625f);
        int rh = y2 - y1 + 1;
        int rw = x2 - x1 + 1;

        // Python floor-div on non-negative ints == C int division here.
        int hs = min(max(y1 + (i * rh) / POOL, 0), FH);
        int he = min(max(y1 + ((i + 1) * rh + POOL - 1) / POOL, 0), FH);
        int ws = min(max(x1 + (j * rw) / POOL, 0), FW);
        int we = min(max(x1 + ((j + 1) * rw + POOL - 1) / POOL, 0), FW);

        float m = -INFINITY;                    // empty bin -> -inf (matches ref)
        for (int h = hs; h < he; ++h)
            for (int w = ws; w < we; ++w)
                m = fmaxf(m, sf[h * FW + w]);
        pooled_g[n * NBINS + t] = m;
    }
}

// K3: pure streaming broadcast writer. No LDS, no barriers. 2450 blocks x 256
// threads x 3 float4 = exactly TOTAL_F4. Value load is L1/L2-hot broadcast;
// stores are perfectly coalesced nontemporal float4.
__global__ __launch_bounds__(256) void write_kernel(
    const float* __restrict__ pooled_g, float* __restrict__ out) {
    int f = blockIdx.x * 768 + threadIdx.x;
    floatx4* o4 = (floatx4*)out;
    #pragma unroll
    for (int k = 0; k < 3; ++k, f += 256) {
        int roi = f / OUT_F4;                   // magic-mul div by 6272
        int bin = (f - roi * OUT_F4) >> 7;      // 128 f4 per bin
        float m = pooled_g[roi * NBINS + bin];
        floatx4 v = {m, m, m, m};
        __builtin_nontemporal_store(v, &o4[f]);
    }
}

extern "C" void kernel_launch(void* const* d_in, const int* in_sizes, int n_in,
                              void* d_out, int out_size, void* d_ws, size_t ws_size,
                              hipStream_t stream) {
    const float* rois = (const float*)d_in[0];          // (300, 5) f32
    const float* feature_maps = (const float*)d_in[1];  // (50, 50, 512) f32
    float* out = (float*)d_out;                         // (300, 7, 7, 512) f32
    float* fmax_g = (float*)d_ws;                       // 2500 floats
    float* pooled_g = (float*)d_ws + 4096;              // 300*49 floats, aligned

    channel_max_kernel<<<FMAX_N / 4, 256, 0, stream>>>(feature_maps, fmax_g);
    pool_kernel<<<NUM_ROIS, 256, 0, stream>>>(rois, fmax_g, pooled_g);
    write_kernel<<<TOTAL_F4 / 768, 256, 0, stream>>>(pooled_g, out);
}

// Round 6
// 71.391 us; speedup vs baseline: 1.1796x; 1.0598x over previous
//
#include <hip/hip_runtime.h>
#include <math.h>

#define POOL 7
#define NUM_ROIS 300
#define FH 50
#define FW 50
#define FC 512
#define NBINS (POOL * POOL)                    // 49 bins per ROI
#define FMAX_N (FH * FW)                       // 2500 pixels
#define ROW_F4 (POOL * FC / 4)                 // 896 float4 per (roi,row-bin)

typedef float floatx4 __attribute__((ext_vector_type(4)));  // native vec for nontemporal

// K1: fmax[h][w] = max over C of feature_maps[h][w][c]
// 256-thread blocks, one wave per pixel (4 pixels/block) -> 625 workgroups, ~2 us.
__global__ __launch_bounds__(256) void channel_max_kernel(
    const float* __restrict__ fm, float* __restrict__ fmax_g) {
    int wave = threadIdx.x >> 6;
    int lane = threadIdx.x & 63;
    int pix = blockIdx.x * 4 + wave;            // 0..2499
    const float4* p = (const float4*)(fm + (size_t)pix * FC);
    float4 a = p[lane];
    float4 b = p[lane + 64];
    float m = fmaxf(fmaxf(fmaxf(a.x, a.y), fmaxf(a.z, a.w)),
                    fmaxf(fmaxf(b.x, b.y), fmaxf(b.z, b.w)));
    #pragma unroll
    for (int off = 32; off > 0; off >>= 1)
        m = fmaxf(m, __shfl_down(m, off, 64));
    if (lane == 0) fmax_g[pix] = m;
}

// K2: one block per (roi, row-bin): 2100 blocks x 256 threads (~8.2/CU).
// Lanes 0..6 compute the 7 col-bin maxima straight from fmax_g (10 KB,
// L1/L2-resident; <=64 loads each, avg ~9). One LDS[7] + one barrier, then
// 896 balanced nontemporal float4 stores (30 MB aggregate = output floor).
__global__ __launch_bounds__(256) void pool_row_kernel(
    const float* __restrict__ rois, const float* __restrict__ fmax_g,
    float* __restrict__ out) {
    __shared__ float pooled[POOL];
    int b = blockIdx.x;
    int n = b / POOL;                           // roi
    int i = b - n * POOL;                       // row bin
    int t = threadIdx.x;

    if (t < POOL) {
        int j = t;                              // col bin (one per lane)

        // Replicate: r = int32(roi * (1/16)) (truncation; values non-negative).
        int x1 = (int)(rois[n * 5 + 1] * 0.0625f);
        int y1 = (int)(rois[n * 5 + 2] * 0.0625f);
        int x2 = (int)(rois[n * 5 + 3] * 0.0625f);
        int y2 = (int)(rois[n * 5 + 4] * 0.0625f);
        int rh = y2 - y1 + 1;
        int rw = x2 - x1 + 1;

        // Python floor-div on non-negative ints == C int division here.
        int hs = min(max(y1 + (i * rh) / POOL, 0), FH);
        int he = min(max(y1 + ((i + 1) * rh + POOL - 1) / POOL, 0), FH);
        int ws = min(max(x1 + (j * rw) / POOL, 0), FW);
        int we = min(max(x1 + ((j + 1) * rw + POOL - 1) / POOL, 0), FW);

        float m = -INFINITY;                    // empty bin -> -inf (matches ref)
        for (int h = hs; h < he; ++h)
            for (int w = ws; w < we; ++w)
                m = fmaxf(m, fmax_g[h * FW + w]);
        pooled[t] = m;
    }
    __syncthreads();

    // Write this (roi,row-bin)'s 7*512 floats = 896 float4; col bin = f >> 7.
    floatx4* o4 = (floatx4*)(out + ((size_t)n * NBINS + (size_t)i * POOL) * FC);
    for (int f = t; f < ROW_F4; f += 256) {
        float m = pooled[f >> 7];
        floatx4 v = {m, m, m, m};
        __builtin_nontemporal_store(v, &o4[f]);
    }
}

extern "C" void kernel_launch(void* const* d_in, const int* in_sizes, int n_in,
                              void* d_out, int out_size, void* d_ws, size_t ws_size,
                              hipStream_t stream) {
    const float* rois = (const float*)d_in[0];          // (300, 5) f32
    const float* feature_maps = (const float*)d_in[1];  // (50, 50, 512) f32
    float* out = (float*)d_out;                         // (300, 7, 7, 512) f32
    float* fmax_g = (float*)d_ws;                       // 2500 floats

    channel_max_kernel<<<FMAX_N / 4, 256, 0, stream>>>(feature_maps, fmax_g);
    pool_row_kernel<<<NUM_ROIS * POOL, 256, 0, stream>>>(rois, fmax_g, out);
}